// Round 10
// baseline (369.749 us; speedup 1.0000x reference)
//
#include <hip/hip_runtime.h>
#include <hip/hip_fp16.h>

// ---------------------------------------------------------------------------
// VGAE encoder, gather-form, fp16 gather table, SPLIT kernels, NT streams.
//   a[i] = dis_i*(g[i] + sum_{e:dst=i} g[src_e]),  g = fp16(dis (.) h)
//   Nontemporal hints on all read-once/write-once streams keep L2 free for
//   the random 64 B row gather (the bottleneck). Layers 1-2 pass `a` in
//   fp16; final layer in fp32. Fusion rejected (R5 occupancy / R7 spill).
//   NT builtins need native scalar/ext-vector types (not HIP_vector_type).
// ---------------------------------------------------------------------------

#define BK_BITS 9
#define BK      (1 << BK_BITS)     // 512 dst nodes per bucket
#define BMASK   (BK - 1)
#define EPT     16
#define CHUNK   (256 * EPT)        // 4096 edges per block
#define CAP     16384              // bucket capacity (mean 8192, max ~8.6k)

typedef int   vint4  __attribute__((ext_vector_type(4)));
typedef uint  vuint4 __attribute__((ext_vector_type(4)));

#define NTL(p)    __builtin_nontemporal_load(p)
#define NTS(v, p) __builtin_nontemporal_store(v, p)

// ---- pass A: scatter edges into capacity-padded dst-buckets ----------------
__global__ void k_bucket(const int* __restrict__ src, const int* __restrict__ dst,
                         int* __restrict__ bcur, int* __restrict__ ebuf, int E) {
    __shared__ int lcnt[256];
    __shared__ int lbase[256];
    int t = threadIdx.x;
    lcnt[t] = 0;
    __syncthreads();
    int e0 = blockIdx.x * CHUNK;
    int pk[EPT];
#pragma unroll
    for (int i = 0; i < EPT; ++i) {
        int e = e0 + i * 256 + t;
        pk[i] = -1;
        if (e < E) {
            int d = NTL(dst + e);
            int b = d >> BK_BITS;
            int off = atomicAdd(&lcnt[b], 1);          // off < CHUNK = 4096
            pk[i] = (b << 21) | (off << BK_BITS) | (d & BMASK);
        }
    }
    __syncthreads();
    lbase[t] = t * CAP + atomicAdd(&bcur[t], lcnt[t]);
    __syncthreads();
#pragma unroll
    for (int i = 0; i < EPT; ++i) {
        int e = e0 + i * 256 + t;
        if (e < E) {
            int b   = pk[i] >> 21;
            int off = (pk[i] >> BK_BITS) & 4095;
            int dl  = pk[i] & BMASK;
            int pos = lbase[b] + off;
            if (pos < (b + 1) * CAP)                  // overflow guard (never hit)
                NTS((NTL(src + e) << BK_BITS) | dl, ebuf + pos);
        }
    }
}

// ---- pass B: per-bucket finalize: starts, dis, sorted src, g0 --------------
__global__ void k_finalize(const int* __restrict__ bcur, int* __restrict__ starts,
                           float* __restrict__ dis, const int* __restrict__ ebuf,
                           int* __restrict__ es, const float* __restrict__ x,
                           __half* __restrict__ g0, int n, int E) {
    __shared__ int   hist[BK];
    __shared__ int   sc[BK];
    __shared__ int   sb[256];
    __shared__ float disL[BK];
    int b = blockIdx.x, t = threadIdx.x;
    if (t < 256) sb[t] = min(bcur[t], CAP);
    hist[t] = 0;
    __syncthreads();
    for (int o = 1; o < 256; o <<= 1) {
        int xv = 0;
        if (t < 256 && t >= o) xv = sb[t - o];
        __syncthreads();
        if (t < 256) sb[t] += xv;
        __syncthreads();
    }
    int cnt = min(bcur[b], CAP);
    int beg = sb[b] - cnt;                  // exclusive scan at b
    const int* eb = ebuf + (size_t)b * CAP;
    for (int j = t; j < cnt; j += BK)
        atomicAdd(&hist[NTL(eb + j) & BMASK], 1);
    __syncthreads();
    int cv = hist[t];
    sc[t] = cv;
    __syncthreads();
    for (int o = 1; o < BK; o <<= 1) {
        int xv = (t >= o) ? sc[t - o] : 0;
        __syncthreads();
        sc[t] += xv;
        __syncthreads();
    }
    int excl = sc[t] - cv;
    int gnode = (b << BK_BITS) + t;
    float dv = rsqrtf((float)cv + 1.0f);    // +1 = self loop
    disL[t] = dv;
    if (gnode < n) {
        starts[gnode] = beg + excl;
        dis[gnode] = dv;
    }
    if (b == 0 && t == 0) starts[n] = E;
    hist[t] = excl;                         // reuse as cursor
    __syncthreads();
    for (int j = t; j < cnt; j += BK) {
        int v = NTL(eb + j);
        int off = atomicAdd(&hist[v & BMASK], 1);
        NTS(v >> BK_BITS, es + beg + off);
    }
    // g0 = fp16(dis (.) x) for this bucket's nodes (coalesced 8 B stores)
    int node0 = b << BK_BITS;
    const float4* x4 = (const float4*)x;
    uint2* g2 = (uint2*)g0;
    for (int idx = t; idx < BK * 8; idx += BK) {
        int r = idx >> 3, lane = idx & 7;
        int nd = node0 + r;
        if (nd < n) {
            float d = disL[r];
            float4 v = x4[(size_t)nd * 8 + lane];
            __half2 lo = __floats2half2_rn(d * v.x, d * v.y);
            __half2 hi = __floats2half2_rn(d * v.z, d * v.w);
            uint2 u;
            u.x = *(unsigned int*)&lo;
            u.y = *(unsigned int*)&hi;
            g2[(size_t)nd * 8 + lane] = u;
        }
    }
}

// ---- gather helper: accumulate 8 halves into fp32 --------------------------
__device__ inline void acc8(uint4 u, float* s) {
    __half2 h0 = *(__half2*)&u.x, h1 = *(__half2*)&u.y;
    __half2 h2 = *(__half2*)&u.z, h3 = *(__half2*)&u.w;
    float2 f0 = __half22float2(h0), f1 = __half22float2(h1);
    float2 f2 = __half22float2(h2), f3 = __half22float2(h3);
    s[0] += f0.x; s[1] += f0.y; s[2] += f1.x; s[3] += f1.y;
    s[4] += f2.x; s[5] += f2.y; s[6] += f3.x; s[7] += f3.y;
}

// ---- aggregation: a[i] = dis_i*(g[i] + sum g[src_e]), fp32 accum -----------
// OUT16: write fp16 (layers 1-2) vs fp32 (final). 4 lanes/node, 64 nodes/block.
template <bool OUT16>
__global__ void k_agg(const int* __restrict__ starts, const int* __restrict__ es,
                      const float* __restrict__ dis, const __half* __restrict__ g,
                      void* __restrict__ outp, int n) {
    int t = threadIdx.x;
    int node = blockIdx.x * 64 + (t >> 2);
    if (node >= n) return;
    int lane = t & 3;
    const uint4* g4 = (const uint4*)g;     // 16 B = 8 halves
    float s[8] = {0, 0, 0, 0, 0, 0, 0, 0};
    acc8(g4[(size_t)node * 4 + lane], s);  // self term
    int j = starts[node], end = starts[node + 1];
    while (j < end && (j & 3)) {           // align to int4 boundary
        acc8(g4[(size_t)NTL(es + j) * 4 + lane], s);
        ++j;
    }
    for (; j + 8 <= end; j += 8) {         // 8 gathers in flight
        vint4 e0 = NTL((const vint4*)(es + j));
        vint4 e1 = NTL((const vint4*)(es + j + 4));
        uint4 u0 = g4[(size_t)e0.x * 4 + lane];
        uint4 u1 = g4[(size_t)e0.y * 4 + lane];
        uint4 u2 = g4[(size_t)e0.z * 4 + lane];
        uint4 u3 = g4[(size_t)e0.w * 4 + lane];
        uint4 u4 = g4[(size_t)e1.x * 4 + lane];
        uint4 u5 = g4[(size_t)e1.y * 4 + lane];
        uint4 u6 = g4[(size_t)e1.z * 4 + lane];
        uint4 u7 = g4[(size_t)e1.w * 4 + lane];
        acc8(u0, s); acc8(u1, s); acc8(u2, s); acc8(u3, s);
        acc8(u4, s); acc8(u5, s); acc8(u6, s); acc8(u7, s);
    }
    if (j + 4 <= end) {
        vint4 e0 = NTL((const vint4*)(es + j));
        uint4 u0 = g4[(size_t)e0.x * 4 + lane];
        uint4 u1 = g4[(size_t)e0.y * 4 + lane];
        uint4 u2 = g4[(size_t)e0.z * 4 + lane];
        uint4 u3 = g4[(size_t)e0.w * 4 + lane];
        acc8(u0, s); acc8(u1, s); acc8(u2, s); acc8(u3, s);
        j += 4;
    }
    for (; j < end; ++j) acc8(g4[(size_t)NTL(es + j) * 4 + lane], s);
    float dd = dis[node];
    if (OUT16) {
        __half2 h0 = __floats2half2_rn(dd * s[0], dd * s[1]);
        __half2 h1 = __floats2half2_rn(dd * s[2], dd * s[3]);
        __half2 h2 = __floats2half2_rn(dd * s[4], dd * s[5]);
        __half2 h3 = __floats2half2_rn(dd * s[6], dd * s[7]);
        vuint4 u;
        u.x = *(unsigned int*)&h0; u.y = *(unsigned int*)&h1;
        u.z = *(unsigned int*)&h2; u.w = *(unsigned int*)&h3;
        NTS(u, (vuint4*)outp + (size_t)node * 4 + lane);
    } else {
        float* op = (float*)outp + (size_t)node * 32 + lane * 8;
#pragma unroll
        for (int i = 0; i < 8; ++i) NTS(dd * s[i], op + i);
    }
}

// ---- dense layers ----------------------------------------------------------

// gout = fp16(dis (.) relu(in @ W + b)), in is fp16 `a` from agg
__global__ void k_gemm32(const __half* __restrict__ in, const float* __restrict__ W,
                         const float* __restrict__ b, const float* __restrict__ dis,
                         __half* __restrict__ gout, int n) {
    __shared__ float Ws[32][33];
    __shared__ float Xs[8][33];
    int t = threadIdx.x;
    for (int i = t; i < 1024; i += 256) Ws[i >> 5][i & 31] = W[i];
    int r = t >> 5, c = t & 31;
    int node = blockIdx.x * 8 + r;
    float xv = 0.f;
    if (node < n) {
        unsigned short hv = NTL((const unsigned short*)in + (size_t)node * 32 + c);
        __half_raw hr; hr.x = hv;
        xv = __half2float(__half(hr));
    }
    Xs[r][c] = xv;
    __syncthreads();
    if (node >= n) return;
    float sum = b[c];
#pragma unroll
    for (int k = 0; k < 32; ++k) sum += Xs[r][k] * Ws[k][c];
    gout[(size_t)node * 32 + c] = __float2half_rn(dis[node] * fmaxf(sum, 0.f));
}

// mu = in@Wmu + bmu -> out[0:n*32] ; lv = in@Wlv + blv -> out[n*32:]  (fp32 in)
__global__ void k_gemm64(const float* __restrict__ in, const float* __restrict__ Wmu,
                         const float* __restrict__ Wlv, const float* __restrict__ bmu,
                         const float* __restrict__ blv, float* __restrict__ out, int n) {
    __shared__ float Ws[32][64];
    __shared__ float Xs[4][33];
    int t = threadIdx.x;
    for (int i = t; i < 1024; i += 256) {
        int k = i >> 5, c = i & 31;
        Ws[k][c]      = Wmu[i];
        Ws[k][c + 32] = Wlv[i];
    }
    if (t < 128) {
        int r = t >> 5, c = t & 31;
        int node = blockIdx.x * 4 + r;
        Xs[r][c] = (node < n) ? NTL(in + (size_t)node * 32 + c) : 0.f;
    }
    __syncthreads();
    int r = t >> 6, c = t & 63;
    int node = blockIdx.x * 4 + r;
    if (node >= n) return;
    float sum = (c < 32) ? bmu[c] : blv[c - 32];
#pragma unroll
    for (int k = 0; k < 32; ++k) sum += Xs[r][k] * Ws[k][c];
    if (c < 32) NTS(sum, out + (size_t)node * 32 + c);
    else        NTS(sum, out + (size_t)n * 32 + (size_t)node * 32 + (c - 32));
}

// ---- launch ----------------------------------------------------------------

extern "C" void kernel_launch(void* const* d_in, const int* in_sizes, int n_in,
                              void* d_out, int out_size, void* d_ws, size_t ws_size,
                              hipStream_t stream) {
    const float* x   = (const float*)d_in[0];
    const int*   ei  = (const int*)d_in[1];
    const float* W1  = (const float*)d_in[2];
    const float* b1  = (const float*)d_in[3];
    const float* W2  = (const float*)d_in[4];
    const float* b2  = (const float*)d_in[5];
    const float* Wmu = (const float*)d_in[6];
    const float* bmu = (const float*)d_in[7];
    const float* Wlv = (const float*)d_in[8];
    const float* blv = (const float*)d_in[9];
    float* out = (float*)d_out;

    int n = in_sizes[0] / 32;   // 100000
    int E = in_sizes[1] / 2;    // 1600000
    const int* src = ei;
    const int* dst = ei + E;
    int nbuck = (n + BK - 1) >> BK_BITS;   // 196 (<= 256)

    // workspace layout (all segments 16B-aligned)
    int*    bcur   = (int*)d_ws;                      // 256
    int     npad   = (n + 4) & ~3;
    int*    starts = bcur + 256;                      // n+1 (padded)
    float*  dis    = (float*)(starts + npad);         // n
    int*    es     = (int*)(dis + n);                 // E
    float*  a32    = (float*)(es + E);                // n*32 fp32 (final layer)
    __half* aH     = (__half*)(a32 + (size_t)n * 32); // n*32 fp16 (layers 1-2)
    __half* gA     = aH + (size_t)n * 32;             // n*32 fp16
    __half* gB     = gA + (size_t)n * 32;             // n*32 fp16
    int*    ebuf   = (int*)(gB + (size_t)n * 32);     // 256*CAP ints (16.8 MB)

    int nblk = (E + CHUNK - 1) / CHUNK;
    int agrid = (n + 63) / 64;

    // ---- edge preprocessing ----
    hipMemsetAsync(bcur, 0, 256 * sizeof(int), stream);
    k_bucket<<<nblk, 256, 0, stream>>>(src, dst, bcur, ebuf, E);
    k_finalize<<<nbuck, BK, 0, stream>>>(bcur, starts, dis, ebuf, es, x, gA, n, E);

    // ---- layer 1 ----
    k_agg<true><<<agrid, 256, 0, stream>>>(starts, es, dis, gA, aH, n);
    k_gemm32<<<(n + 7) / 8, 256, 0, stream>>>(aH, W1, b1, dis, gB, n);

    // ---- layer 2 ----
    k_agg<true><<<agrid, 256, 0, stream>>>(starts, es, dis, gB, aH, n);
    k_gemm32<<<(n + 7) / 8, 256, 0, stream>>>(aH, W2, b2, dis, gA, n);

    // ---- mu/logvar ----
    k_agg<false><<<agrid, 256, 0, stream>>>(starts, es, dis, gA, a32, n);
    k_gemm64<<<(n + 3) / 4, 256, 0, stream>>>(a32, Wmu, Wlv, bmu, blv, out, n);
}

// Round 11
// 318.438 us; speedup vs baseline: 1.1611x; 1.1611x over previous
//
#include <hip/hip_runtime.h>
#include <hip/hip_fp16.h>

// ---------------------------------------------------------------------------
// VGAE encoder, gather-form, fp16 gather table, SPLIT kernels.
//   a[i] = dis_i*(g[i] + sum_{e:dst=i} g[src_e]),  g = fp16(dis (.) h)
//   NT LOADS only on read-once streams (es/ebuf/src/dst/a) to keep L2 for
//   the random 64 B row gather. NT STORES removed entirely — R10 showed NT
//   scattered stores write through per-store (125 MB for 13 MB of data).
//   Layers 1-2 pass `a` in fp16; final layer fp32. Fusion rejected (R5/R7).
// ---------------------------------------------------------------------------

#define BK_BITS 9
#define BK      (1 << BK_BITS)     // 512 dst nodes per bucket
#define BMASK   (BK - 1)
#define EPT     16
#define CHUNK   (256 * EPT)        // 4096 edges per block
#define CAP     16384              // bucket capacity (mean 8192, max ~8.6k)

typedef int vint4 __attribute__((ext_vector_type(4)));

#define NTL(p) __builtin_nontemporal_load(p)

// ---- pass A: scatter edges into capacity-padded dst-buckets ----------------
__global__ void k_bucket(const int* __restrict__ src, const int* __restrict__ dst,
                         int* __restrict__ bcur, int* __restrict__ ebuf, int E) {
    __shared__ int lcnt[256];
    __shared__ int lbase[256];
    int t = threadIdx.x;
    lcnt[t] = 0;
    __syncthreads();
    int e0 = blockIdx.x * CHUNK;
    int pk[EPT];
#pragma unroll
    for (int i = 0; i < EPT; ++i) {
        int e = e0 + i * 256 + t;
        pk[i] = -1;
        if (e < E) {
            int d = NTL(dst + e);
            int b = d >> BK_BITS;
            int off = atomicAdd(&lcnt[b], 1);          // off < CHUNK = 4096
            pk[i] = (b << 21) | (off << BK_BITS) | (d & BMASK);
        }
    }
    __syncthreads();
    lbase[t] = t * CAP + atomicAdd(&bcur[t], lcnt[t]);
    __syncthreads();
#pragma unroll
    for (int i = 0; i < EPT; ++i) {
        int e = e0 + i * 256 + t;
        if (e < E) {
            int b   = pk[i] >> 21;
            int off = (pk[i] >> BK_BITS) & 4095;
            int dl  = pk[i] & BMASK;
            int pos = lbase[b] + off;
            if (pos < (b + 1) * CAP)                  // overflow guard (never hit)
                ebuf[pos] = (NTL(src + e) << BK_BITS) | dl;
        }
    }
}

// ---- pass B: per-bucket finalize: starts, dis, sorted src, g0 --------------
__global__ void k_finalize(const int* __restrict__ bcur, int* __restrict__ starts,
                           float* __restrict__ dis, const int* __restrict__ ebuf,
                           int* __restrict__ es, const float* __restrict__ x,
                           __half* __restrict__ g0, int n, int E) {
    __shared__ int   hist[BK];
    __shared__ int   sc[BK];
    __shared__ int   sb[256];
    __shared__ float disL[BK];
    int b = blockIdx.x, t = threadIdx.x;
    if (t < 256) sb[t] = min(bcur[t], CAP);
    hist[t] = 0;
    __syncthreads();
    for (int o = 1; o < 256; o <<= 1) {
        int xv = 0;
        if (t < 256 && t >= o) xv = sb[t - o];
        __syncthreads();
        if (t < 256) sb[t] += xv;
        __syncthreads();
    }
    int cnt = min(bcur[b], CAP);
    int beg = sb[b] - cnt;                  // exclusive scan at b
    const int* eb = ebuf + (size_t)b * CAP;
    for (int j = t; j < cnt; j += BK)
        atomicAdd(&hist[NTL(eb + j) & BMASK], 1);
    __syncthreads();
    int cv = hist[t];
    sc[t] = cv;
    __syncthreads();
    for (int o = 1; o < BK; o <<= 1) {
        int xv = (t >= o) ? sc[t - o] : 0;
        __syncthreads();
        sc[t] += xv;
        __syncthreads();
    }
    int excl = sc[t] - cv;
    int gnode = (b << BK_BITS) + t;
    float dv = rsqrtf((float)cv + 1.0f);    // +1 = self loop
    disL[t] = dv;
    if (gnode < n) {
        starts[gnode] = beg + excl;
        dis[gnode] = dv;
    }
    if (b == 0 && t == 0) starts[n] = E;
    hist[t] = excl;                         // reuse as cursor
    __syncthreads();
    for (int j = t; j < cnt; j += BK) {
        int v = NTL(eb + j);
        int off = atomicAdd(&hist[v & BMASK], 1);
        es[beg + off] = v >> BK_BITS;       // normal store: L2 combines
    }
    // g0 = fp16(dis (.) x) for this bucket's nodes (coalesced 8 B stores)
    int node0 = b << BK_BITS;
    const float4* x4 = (const float4*)x;
    uint2* g2 = (uint2*)g0;
    for (int idx = t; idx < BK * 8; idx += BK) {
        int r = idx >> 3, lane = idx & 7;
        int nd = node0 + r;
        if (nd < n) {
            float d = disL[r];
            float4 v = x4[(size_t)nd * 8 + lane];
            __half2 lo = __floats2half2_rn(d * v.x, d * v.y);
            __half2 hi = __floats2half2_rn(d * v.z, d * v.w);
            uint2 u;
            u.x = *(unsigned int*)&lo;
            u.y = *(unsigned int*)&hi;
            g2[(size_t)nd * 8 + lane] = u;
        }
    }
}

// ---- gather helper: accumulate 8 halves into fp32 --------------------------
__device__ inline void acc8(uint4 u, float* s) {
    __half2 h0 = *(__half2*)&u.x, h1 = *(__half2*)&u.y;
    __half2 h2 = *(__half2*)&u.z, h3 = *(__half2*)&u.w;
    float2 f0 = __half22float2(h0), f1 = __half22float2(h1);
    float2 f2 = __half22float2(h2), f3 = __half22float2(h3);
    s[0] += f0.x; s[1] += f0.y; s[2] += f1.x; s[3] += f1.y;
    s[4] += f2.x; s[5] += f2.y; s[6] += f3.x; s[7] += f3.y;
}

// ---- aggregation: a[i] = dis_i*(g[i] + sum g[src_e]), fp32 accum -----------
// OUT16: write fp16 (layers 1-2) vs fp32 (final). 4 lanes/node, 64 nodes/block.
template <bool OUT16>
__global__ void k_agg(const int* __restrict__ starts, const int* __restrict__ es,
                      const float* __restrict__ dis, const __half* __restrict__ g,
                      void* __restrict__ outp, int n) {
    int t = threadIdx.x;
    int node = blockIdx.x * 64 + (t >> 2);
    if (node >= n) return;
    int lane = t & 3;
    const uint4* g4 = (const uint4*)g;     // 16 B = 8 halves
    float s[8] = {0, 0, 0, 0, 0, 0, 0, 0};
    acc8(g4[(size_t)node * 4 + lane], s);  // self term
    int j = starts[node], end = starts[node + 1];
    while (j < end && (j & 3)) {           // align to int4 boundary
        acc8(g4[(size_t)NTL(es + j) * 4 + lane], s);
        ++j;
    }
    for (; j + 8 <= end; j += 8) {         // 8 gathers in flight
        vint4 e0 = NTL((const vint4*)(es + j));
        vint4 e1 = NTL((const vint4*)(es + j + 4));
        uint4 u0 = g4[(size_t)e0.x * 4 + lane];
        uint4 u1 = g4[(size_t)e0.y * 4 + lane];
        uint4 u2 = g4[(size_t)e0.z * 4 + lane];
        uint4 u3 = g4[(size_t)e0.w * 4 + lane];
        uint4 u4 = g4[(size_t)e1.x * 4 + lane];
        uint4 u5 = g4[(size_t)e1.y * 4 + lane];
        uint4 u6 = g4[(size_t)e1.z * 4 + lane];
        uint4 u7 = g4[(size_t)e1.w * 4 + lane];
        acc8(u0, s); acc8(u1, s); acc8(u2, s); acc8(u3, s);
        acc8(u4, s); acc8(u5, s); acc8(u6, s); acc8(u7, s);
    }
    if (j + 4 <= end) {
        vint4 e0 = NTL((const vint4*)(es + j));
        uint4 u0 = g4[(size_t)e0.x * 4 + lane];
        uint4 u1 = g4[(size_t)e0.y * 4 + lane];
        uint4 u2 = g4[(size_t)e0.z * 4 + lane];
        uint4 u3 = g4[(size_t)e0.w * 4 + lane];
        acc8(u0, s); acc8(u1, s); acc8(u2, s); acc8(u3, s);
        j += 4;
    }
    for (; j < end; ++j) acc8(g4[(size_t)NTL(es + j) * 4 + lane], s);
    float dd = dis[node];
    if (OUT16) {
        __half2 h0 = __floats2half2_rn(dd * s[0], dd * s[1]);
        __half2 h1 = __floats2half2_rn(dd * s[2], dd * s[3]);
        __half2 h2 = __floats2half2_rn(dd * s[4], dd * s[5]);
        __half2 h3 = __floats2half2_rn(dd * s[6], dd * s[7]);
        uint4 u;
        u.x = *(unsigned int*)&h0; u.y = *(unsigned int*)&h1;
        u.z = *(unsigned int*)&h2; u.w = *(unsigned int*)&h3;
        ((uint4*)outp)[(size_t)node * 4 + lane] = u;
    } else {
        float4 o0 = make_float4(dd * s[0], dd * s[1], dd * s[2], dd * s[3]);
        float4 o1 = make_float4(dd * s[4], dd * s[5], dd * s[6], dd * s[7]);
        float4* op = (float4*)outp + (size_t)node * 8 + lane * 2;
        op[0] = o0;
        op[1] = o1;
    }
}

// ---- dense layers ----------------------------------------------------------

// gout = fp16(dis (.) relu(in @ W + b)), in is fp16 `a` from agg
__global__ void k_gemm32(const __half* __restrict__ in, const float* __restrict__ W,
                         const float* __restrict__ b, const float* __restrict__ dis,
                         __half* __restrict__ gout, int n) {
    __shared__ float Ws[32][33];
    __shared__ float Xs[8][33];
    int t = threadIdx.x;
    for (int i = t; i < 1024; i += 256) Ws[i >> 5][i & 31] = W[i];
    int r = t >> 5, c = t & 31;
    int node = blockIdx.x * 8 + r;
    float xv = 0.f;
    if (node < n) {
        unsigned short hv = NTL((const unsigned short*)in + (size_t)node * 32 + c);
        __half_raw hr; hr.x = hv;
        xv = __half2float(__half(hr));
    }
    Xs[r][c] = xv;
    __syncthreads();
    if (node >= n) return;
    float sum = b[c];
#pragma unroll
    for (int k = 0; k < 32; ++k) sum += Xs[r][k] * Ws[k][c];
    gout[(size_t)node * 32 + c] = __float2half_rn(dis[node] * fmaxf(sum, 0.f));
}

// mu = in@Wmu + bmu -> out[0:n*32] ; lv = in@Wlv + blv -> out[n*32:]  (fp32 in)
__global__ void k_gemm64(const float* __restrict__ in, const float* __restrict__ Wmu,
                         const float* __restrict__ Wlv, const float* __restrict__ bmu,
                         const float* __restrict__ blv, float* __restrict__ out, int n) {
    __shared__ float Ws[32][64];
    __shared__ float Xs[4][33];
    int t = threadIdx.x;
    for (int i = t; i < 1024; i += 256) {
        int k = i >> 5, c = i & 31;
        Ws[k][c]      = Wmu[i];
        Ws[k][c + 32] = Wlv[i];
    }
    if (t < 128) {
        int r = t >> 5, c = t & 31;
        int node = blockIdx.x * 4 + r;
        Xs[r][c] = (node < n) ? NTL(in + (size_t)node * 32 + c) : 0.f;
    }
    __syncthreads();
    int r = t >> 6, c = t & 63;
    int node = blockIdx.x * 4 + r;
    if (node >= n) return;
    float sum = (c < 32) ? bmu[c] : blv[c - 32];
#pragma unroll
    for (int k = 0; k < 32; ++k) sum += Xs[r][k] * Ws[k][c];
    if (c < 32) out[(size_t)node * 32 + c] = sum;
    else        out[(size_t)n * 32 + (size_t)node * 32 + (c - 32)] = sum;
}

// ---- launch ----------------------------------------------------------------

extern "C" void kernel_launch(void* const* d_in, const int* in_sizes, int n_in,
                              void* d_out, int out_size, void* d_ws, size_t ws_size,
                              hipStream_t stream) {
    const float* x   = (const float*)d_in[0];
    const int*   ei  = (const int*)d_in[1];
    const float* W1  = (const float*)d_in[2];
    const float* b1  = (const float*)d_in[3];
    const float* W2  = (const float*)d_in[4];
    const float* b2  = (const float*)d_in[5];
    const float* Wmu = (const float*)d_in[6];
    const float* bmu = (const float*)d_in[7];
    const float* Wlv = (const float*)d_in[8];
    const float* blv = (const float*)d_in[9];
    float* out = (float*)d_out;

    int n = in_sizes[0] / 32;   // 100000
    int E = in_sizes[1] / 2;    // 1600000
    const int* src = ei;
    const int* dst = ei + E;
    int nbuck = (n + BK - 1) >> BK_BITS;   // 196 (<= 256)

    // workspace layout (all segments 16B-aligned)
    int*    bcur   = (int*)d_ws;                      // 256
    int     npad   = (n + 4) & ~3;
    int*    starts = bcur + 256;                      // n+1 (padded)
    float*  dis    = (float*)(starts + npad);         // n
    int*    es     = (int*)(dis + n);                 // E
    float*  a32    = (float*)(es + E);                // n*32 fp32 (final layer)
    __half* aH     = (__half*)(a32 + (size_t)n * 32); // n*32 fp16 (layers 1-2)
    __half* gA     = aH + (size_t)n * 32;             // n*32 fp16
    __half* gB     = gA + (size_t)n * 32;             // n*32 fp16
    int*    ebuf   = (int*)(gB + (size_t)n * 32);     // 256*CAP ints (16.8 MB)

    int nblk = (E + CHUNK - 1) / CHUNK;
    int agrid = (n + 63) / 64;

    // ---- edge preprocessing ----
    hipMemsetAsync(bcur, 0, 256 * sizeof(int), stream);
    k_bucket<<<nblk, 256, 0, stream>>>(src, dst, bcur, ebuf, E);
    k_finalize<<<nbuck, BK, 0, stream>>>(bcur, starts, dis, ebuf, es, x, gA, n, E);

    // ---- layer 1 ----
    k_agg<true><<<agrid, 256, 0, stream>>>(starts, es, dis, gA, aH, n);
    k_gemm32<<<(n + 7) / 8, 256, 0, stream>>>(aH, W1, b1, dis, gB, n);

    // ---- layer 2 ----
    k_agg<true><<<agrid, 256, 0, stream>>>(starts, es, dis, gB, aH, n);
    k_gemm32<<<(n + 7) / 8, 256, 0, stream>>>(aH, W2, b2, dis, gA, n);

    // ---- mu/logvar ----
    k_agg<false><<<agrid, 256, 0, stream>>>(starts, es, dis, gA, a32, n);
    k_gemm64<<<(n + 3) / 4, 256, 0, stream>>>(a32, Wmu, Wlv, bmu, blv, out, n);
}

// Round 12
// 291.984 us; speedup vs baseline: 1.2663x; 1.0906x over previous
//
#include <hip/hip_runtime.h>
#include <hip/hip_fp16.h>

// ---------------------------------------------------------------------------
// VGAE encoder, gather-form, fp16 gather table, SPLIT kernels.
//   a[i] = dis_i*(g[i] + sum_{e:dst=i} g[src_e]),  g = fp16(dis (.) h)
//   GEMMs are grid-stride persistent blocks: W loaded to LDS once per block,
//   then many node tiles (R11 showed 25k tiny blocks cost 44 us in gemm64).
//   NT loads ONLY on read-once streams (src/dst, gemm activation input);
//   es/ebuf are re-read and must stay cacheable. NT stores banned (R10).
//   Fusion of gather+GEMM rejected (R5 occupancy / R7 spill).
// ---------------------------------------------------------------------------

#define BK_BITS 9
#define BK      (1 << BK_BITS)     // 512 dst nodes per bucket
#define BMASK   (BK - 1)
#define EPT     16
#define CHUNK   (256 * EPT)        // 4096 edges per block
#define CAP     16384              // bucket capacity (mean 8192, max ~8.6k)

typedef int   vint4   __attribute__((ext_vector_type(4)));
typedef uint  vuint4  __attribute__((ext_vector_type(4)));
typedef float vfloat4 __attribute__((ext_vector_type(4)));

#define NTL(p) __builtin_nontemporal_load(p)

// ---- pass A: scatter edges into capacity-padded dst-buckets ----------------
__global__ void k_bucket(const int* __restrict__ src, const int* __restrict__ dst,
                         int* __restrict__ bcur, int* __restrict__ ebuf, int E) {
    __shared__ int lcnt[256];
    __shared__ int lbase[256];
    int t = threadIdx.x;
    lcnt[t] = 0;
    __syncthreads();
    int e0 = blockIdx.x * CHUNK;
    int pk[EPT];
#pragma unroll
    for (int i = 0; i < EPT; ++i) {
        int e = e0 + i * 256 + t;
        pk[i] = -1;
        if (e < E) {
            int d = NTL(dst + e);
            int b = d >> BK_BITS;
            int off = atomicAdd(&lcnt[b], 1);          // off < CHUNK = 4096
            pk[i] = (b << 21) | (off << BK_BITS) | (d & BMASK);
        }
    }
    __syncthreads();
    lbase[t] = t * CAP + atomicAdd(&bcur[t], lcnt[t]);
    __syncthreads();
#pragma unroll
    for (int i = 0; i < EPT; ++i) {
        int e = e0 + i * 256 + t;
        if (e < E) {
            int b   = pk[i] >> 21;
            int off = (pk[i] >> BK_BITS) & 4095;
            int dl  = pk[i] & BMASK;
            int pos = lbase[b] + off;
            if (pos < (b + 1) * CAP)                  // overflow guard (never hit)
                ebuf[pos] = (NTL(src + e) << BK_BITS) | dl;
        }
    }
}

// ---- pass B: per-bucket finalize: starts, dis, sorted src, g0 --------------
__global__ void k_finalize(const int* __restrict__ bcur, int* __restrict__ starts,
                           float* __restrict__ dis, const int* __restrict__ ebuf,
                           int* __restrict__ es, const float* __restrict__ x,
                           __half* __restrict__ g0, int n, int E) {
    __shared__ int   hist[BK];
    __shared__ int   sc[BK];
    __shared__ int   sb[256];
    __shared__ float disL[BK];
    int b = blockIdx.x, t = threadIdx.x;
    if (t < 256) sb[t] = min(bcur[t], CAP);
    hist[t] = 0;
    __syncthreads();
    for (int o = 1; o < 256; o <<= 1) {
        int xv = 0;
        if (t < 256 && t >= o) xv = sb[t - o];
        __syncthreads();
        if (t < 256) sb[t] += xv;
        __syncthreads();
    }
    int cnt = min(bcur[b], CAP);
    int beg = sb[b] - cnt;                  // exclusive scan at b
    const int* eb = ebuf + (size_t)b * CAP;
    for (int j = t; j < cnt; j += BK)
        atomicAdd(&hist[eb[j] & BMASK], 1);
    __syncthreads();
    int cv = hist[t];
    sc[t] = cv;
    __syncthreads();
    for (int o = 1; o < BK; o <<= 1) {
        int xv = (t >= o) ? sc[t - o] : 0;
        __syncthreads();
        sc[t] += xv;
        __syncthreads();
    }
    int excl = sc[t] - cv;
    int gnode = (b << BK_BITS) + t;
    float dv = rsqrtf((float)cv + 1.0f);    // +1 = self loop
    disL[t] = dv;
    if (gnode < n) {
        starts[gnode] = beg + excl;
        dis[gnode] = dv;
    }
    if (b == 0 && t == 0) starts[n] = E;
    hist[t] = excl;                         // reuse as cursor
    __syncthreads();
    for (int j = t; j < cnt; j += BK) {
        int v = eb[j];
        int off = atomicAdd(&hist[v & BMASK], 1);
        es[beg + off] = v >> BK_BITS;       // normal store: L2 combines
    }
    // g0 = fp16(dis (.) x) for this bucket's nodes (coalesced 8 B stores)
    int node0 = b << BK_BITS;
    const float4* x4 = (const float4*)x;
    uint2* g2 = (uint2*)g0;
    for (int idx = t; idx < BK * 8; idx += BK) {
        int r = idx >> 3, lane = idx & 7;
        int nd = node0 + r;
        if (nd < n) {
            float d = disL[r];
            float4 v = x4[(size_t)nd * 8 + lane];
            __half2 lo = __floats2half2_rn(d * v.x, d * v.y);
            __half2 hi = __floats2half2_rn(d * v.z, d * v.w);
            uint2 u;
            u.x = *(unsigned int*)&lo;
            u.y = *(unsigned int*)&hi;
            g2[(size_t)nd * 8 + lane] = u;
        }
    }
}

// ---- gather helper: accumulate 8 halves into fp32 --------------------------
__device__ inline void acc8(uint4 u, float* s) {
    __half2 h0 = *(__half2*)&u.x, h1 = *(__half2*)&u.y;
    __half2 h2 = *(__half2*)&u.z, h3 = *(__half2*)&u.w;
    float2 f0 = __half22float2(h0), f1 = __half22float2(h1);
    float2 f2 = __half22float2(h2), f3 = __half22float2(h3);
    s[0] += f0.x; s[1] += f0.y; s[2] += f1.x; s[3] += f1.y;
    s[4] += f2.x; s[5] += f2.y; s[6] += f3.x; s[7] += f3.y;
}

// ---- aggregation: a[i] = dis_i*(g[i] + sum g[src_e]), fp32 accum -----------
// OUT16: write fp16 (layers 1-2) vs fp32 (final). 4 lanes/node, 64 nodes/block.
template <bool OUT16>
__global__ void k_agg(const int* __restrict__ starts, const int* __restrict__ es,
                      const float* __restrict__ dis, const __half* __restrict__ g,
                      void* __restrict__ outp, int n) {
    int t = threadIdx.x;
    int node = blockIdx.x * 64 + (t >> 2);
    if (node >= n) return;
    int lane = t & 3;
    const uint4* g4 = (const uint4*)g;     // 16 B = 8 halves
    float s[8] = {0, 0, 0, 0, 0, 0, 0, 0};
    acc8(g4[(size_t)node * 4 + lane], s);  // self term
    int j = starts[node], end = starts[node + 1];
    while (j < end && (j & 3)) {           // align to int4 boundary
        acc8(g4[(size_t)es[j] * 4 + lane], s);
        ++j;
    }
    for (; j + 8 <= end; j += 8) {         // 8 gathers in flight
        int4 e0 = *(const int4*)(es + j);
        int4 e1 = *(const int4*)(es + j + 4);
        uint4 u0 = g4[(size_t)e0.x * 4 + lane];
        uint4 u1 = g4[(size_t)e0.y * 4 + lane];
        uint4 u2 = g4[(size_t)e0.z * 4 + lane];
        uint4 u3 = g4[(size_t)e0.w * 4 + lane];
        uint4 u4 = g4[(size_t)e1.x * 4 + lane];
        uint4 u5 = g4[(size_t)e1.y * 4 + lane];
        uint4 u6 = g4[(size_t)e1.z * 4 + lane];
        uint4 u7 = g4[(size_t)e1.w * 4 + lane];
        acc8(u0, s); acc8(u1, s); acc8(u2, s); acc8(u3, s);
        acc8(u4, s); acc8(u5, s); acc8(u6, s); acc8(u7, s);
    }
    if (j + 4 <= end) {
        int4 e0 = *(const int4*)(es + j);
        uint4 u0 = g4[(size_t)e0.x * 4 + lane];
        uint4 u1 = g4[(size_t)e0.y * 4 + lane];
        uint4 u2 = g4[(size_t)e0.z * 4 + lane];
        uint4 u3 = g4[(size_t)e0.w * 4 + lane];
        acc8(u0, s); acc8(u1, s); acc8(u2, s); acc8(u3, s);
        j += 4;
    }
    for (; j < end; ++j) acc8(g4[(size_t)es[j] * 4 + lane], s);
    float dd = dis[node];
    if (OUT16) {
        __half2 h0 = __floats2half2_rn(dd * s[0], dd * s[1]);
        __half2 h1 = __floats2half2_rn(dd * s[2], dd * s[3]);
        __half2 h2 = __floats2half2_rn(dd * s[4], dd * s[5]);
        __half2 h3 = __floats2half2_rn(dd * s[6], dd * s[7]);
        uint4 u;
        u.x = *(unsigned int*)&h0; u.y = *(unsigned int*)&h1;
        u.z = *(unsigned int*)&h2; u.w = *(unsigned int*)&h3;
        ((uint4*)outp)[(size_t)node * 4 + lane] = u;
    } else {
        float4 o0 = make_float4(dd * s[0], dd * s[1], dd * s[2], dd * s[3]);
        float4 o1 = make_float4(dd * s[4], dd * s[5], dd * s[6], dd * s[7]);
        float4* op = (float4*)outp + (size_t)node * 8 + lane * 2;
        op[0] = o0;
        op[1] = o1;
    }
}

// ---- dense layers (grid-stride persistent blocks) ---------------------------

// gout = fp16(dis (.) relu(in @ W + b)); 32-node tiles, 4 outputs/thread
__global__ void k_gemm32(const __half* __restrict__ in, const float* __restrict__ W,
                         const float* __restrict__ bias, const float* __restrict__ dis,
                         __half* __restrict__ gout, int n, int ntiles) {
    __shared__ float Ws[32][33];
    __shared__ float Xs[32][33];
    int t = threadIdx.x;
    for (int i = t; i < 1024; i += 256) Ws[i >> 5][i & 31] = W[i];
    int c = t & 31;
    int rbase = t >> 5;                       // 0..7
    float bc = bias[c];
    for (int tile = blockIdx.x; tile < ntiles; tile += gridDim.x) {
        int node0 = tile * 32;
        __syncthreads();                      // prev compute done
        if (t < 128) {                        // load 32 nodes x 32ch fp16
            int r = t >> 2, seg = t & 3;
            int node = node0 + r;
            float f[8] = {0, 0, 0, 0, 0, 0, 0, 0};
            if (node < n) {
                vuint4 u = NTL((const vuint4*)in + (size_t)node * 4 + seg);
                unsigned int w[4] = {u.x, u.y, u.z, u.w};
#pragma unroll
                for (int i = 0; i < 4; ++i) {
                    float2 ff = __half22float2(*(__half2*)&w[i]);
                    f[2 * i] = ff.x; f[2 * i + 1] = ff.y;
                }
            }
#pragma unroll
            for (int i = 0; i < 8; ++i) Xs[r][seg * 8 + i] = f[i];
        }
        __syncthreads();
#pragma unroll
        for (int rr = 0; rr < 4; ++rr) {
            int r = rbase + rr * 8;
            int node = node0 + r;
            if (node >= n) continue;
            float sum = bc;
#pragma unroll
            for (int k = 0; k < 32; ++k) sum += Xs[r][k] * Ws[k][c];
            gout[(size_t)node * 32 + c] = __float2half_rn(dis[node] * fmaxf(sum, 0.f));
        }
    }
}

// mu|lv = in@[Wmu|Wlv]+bias; 16-node tiles, 4 outputs/thread (fp32 in)
__global__ void k_gemm64(const float* __restrict__ in, const float* __restrict__ Wmu,
                         const float* __restrict__ Wlv, const float* __restrict__ bmu,
                         const float* __restrict__ blv, float* __restrict__ out,
                         int n, int ntiles) {
    __shared__ float Ws[32][64];
    __shared__ float Xs[16][33];
    int t = threadIdx.x;
    for (int i = t; i < 1024; i += 256) {
        int k = i >> 5, cc = i & 31;
        Ws[k][cc]      = Wmu[i];
        Ws[k][cc + 32] = Wlv[i];
    }
    int c = t & 63;
    int rbase = t >> 6;                       // 0..3
    float bc = (c < 32) ? bmu[c] : blv[c - 32];
    for (int tile = blockIdx.x; tile < ntiles; tile += gridDim.x) {
        int node0 = tile * 16;
        __syncthreads();
        if (t < 128) {                        // load 16 nodes x 32ch fp32
            int r = t >> 3, seg = t & 7;
            int node = node0 + r;
            vfloat4 v = {0.f, 0.f, 0.f, 0.f};
            if (node < n) v = NTL((const vfloat4*)in + (size_t)node * 8 + seg);
            Xs[r][seg * 4]     = v.x;
            Xs[r][seg * 4 + 1] = v.y;
            Xs[r][seg * 4 + 2] = v.z;
            Xs[r][seg * 4 + 3] = v.w;
        }
        __syncthreads();
#pragma unroll
        for (int rr = 0; rr < 4; ++rr) {
            int r = rbase + rr * 4;
            int node = node0 + r;
            if (node >= n) continue;
            float sum = bc;
#pragma unroll
            for (int k = 0; k < 32; ++k) sum += Xs[r][k] * Ws[k][c];
            if (c < 32) out[(size_t)node * 32 + c] = sum;
            else        out[(size_t)n * 32 + (size_t)node * 32 + (c - 32)] = sum;
        }
    }
}

// ---- launch ----------------------------------------------------------------

extern "C" void kernel_launch(void* const* d_in, const int* in_sizes, int n_in,
                              void* d_out, int out_size, void* d_ws, size_t ws_size,
                              hipStream_t stream) {
    const float* x   = (const float*)d_in[0];
    const int*   ei  = (const int*)d_in[1];
    const float* W1  = (const float*)d_in[2];
    const float* b1  = (const float*)d_in[3];
    const float* W2  = (const float*)d_in[4];
    const float* b2  = (const float*)d_in[5];
    const float* Wmu = (const float*)d_in[6];
    const float* bmu = (const float*)d_in[7];
    const float* Wlv = (const float*)d_in[8];
    const float* blv = (const float*)d_in[9];
    float* out = (float*)d_out;

    int n = in_sizes[0] / 32;   // 100000
    int E = in_sizes[1] / 2;    // 1600000
    const int* src = ei;
    const int* dst = ei + E;
    int nbuck = (n + BK - 1) >> BK_BITS;   // 196 (<= 256)

    // workspace layout (all segments 16B-aligned)
    int*    bcur   = (int*)d_ws;                      // 256
    int     npad   = (n + 4) & ~3;
    int*    starts = bcur + 256;                      // n+1 (padded)
    float*  dis    = (float*)(starts + npad);         // n
    int*    es     = (int*)(dis + n);                 // E
    float*  a32    = (float*)(es + E);                // n*32 fp32 (final layer)
    __half* aH     = (__half*)(a32 + (size_t)n * 32); // n*32 fp16 (layers 1-2)
    __half* gA     = aH + (size_t)n * 32;             // n*32 fp16
    __half* gB     = gA + (size_t)n * 32;             // n*32 fp16
    int*    ebuf   = (int*)(gB + (size_t)n * 32);     // 256*CAP ints (16.8 MB)

    int nblk = (E + CHUNK - 1) / CHUNK;
    int agrid = (n + 63) / 64;
    int t32 = (n + 31) / 32;   // gemm32 tiles
    int t64 = (n + 15) / 16;   // gemm64 tiles

    // ---- edge preprocessing ----
    hipMemsetAsync(bcur, 0, 256 * sizeof(int), stream);
    k_bucket<<<nblk, 256, 0, stream>>>(src, dst, bcur, ebuf, E);
    k_finalize<<<nbuck, BK, 0, stream>>>(bcur, starts, dis, ebuf, es, x, gA, n, E);

    // ---- layer 1 ----
    k_agg<true><<<agrid, 256, 0, stream>>>(starts, es, dis, gA, aH, n);
    k_gemm32<<<1280, 256, 0, stream>>>(aH, W1, b1, dis, gB, n, t32);

    // ---- layer 2 ----
    k_agg<true><<<agrid, 256, 0, stream>>>(starts, es, dis, gB, aH, n);
    k_gemm32<<<1280, 256, 0, stream>>>(aH, W2, b2, dis, gA, n, t32);

    // ---- mu/logvar ----
    k_agg<false><<<agrid, 256, 0, stream>>>(starts, es, dis, gA, a32, n);
    k_gemm64<<<1280, 256, 0, stream>>>(a32, Wmu, Wlv, bmu, blv, out, n, t64);
}